// Round 3
// baseline (1940.252 us; speedup 1.0000x reference)
//
#include <hip/hip_runtime.h>

// ---------------------------------------------------------------------------
// ReLU-RNN (B=256, T=512, I=64, H=512, O=24), fp32 in/out.  Round 8.
//
// 16 groups (16 batch rows) x 4 members (128 hid cols) = 64 blocks x 256 thr.
//   [round-8] NM 8->4: halves exchange traffic, poll targets, retry spans,
//             and member skew; doubles per-block MFMA (cheap).
//   [round-8] v_cvt_pk_bf16_f32 everywhere for fp32->bf16 hi/lo packing
//             (~5x fewer VALU ops on the inter-barrier critical path).
// Exchange = tagged fp32 (sign bit = slab-parity tag; h>=0 after relu):
//   * flags (agent-scope, 3 polling threads) throttle the wait
//   * sign-bit tags carry data-freshness correctness
//   * phase-1 SPECULATIVE partner loads issued before the poll
//   * phase-2 bounded per-thread tag-retry fixes stale spans
//   * producer: tagged dword stores + flag store with NO vmcnt drain.
// LDS A-planes double-buffered by parity -> 2 barriers/step.
// W_ext=[W_hh|W_ih] (K=576, 2 col-tiles) in VGPRs as bf16 hi/lo; bf16x3 MFMA.
// ---------------------------------------------------------------------------

#define T_STEPS 512
#define NG      16
#define NM      4
#define SLAB    32768                    // 16 rows x 512 cols fp32
#define FLAGS_OFF (2 * NG * SLAB)        // 1 MiB
#define NEG_OFF  (FLAGS_OFF + NG * 64)
#define POLL_CAP 100000
#define TAG_CAP  20000
#define NEG_CAP  20000000

// LDS: A planes double-buffered by parity; rows 16 x 1040B (512 bf16 + 8 pad)
#define LA_STRIDE 1040
#define LA_PLANE  16640                  // 16*1040
#define LA_PAR    33280                  // 2*LA_PLANE (hi+lo)
#define LX_OFF    66560                  // 2*LA_PAR
#define LX_STRIDE 144
#define LX_PLANE  2304                   // 16*144; total 71168 B

typedef short          short8  __attribute__((ext_vector_type(8)));
typedef unsigned short bfx4    __attribute__((ext_vector_type(4)));
typedef unsigned       uintx4  __attribute__((ext_vector_type(4)));
typedef float          floatx4 __attribute__((ext_vector_type(4)));
typedef unsigned long long ull;

__device__ __forceinline__ unsigned short f2bf(float x) {
    unsigned u = __float_as_uint(x);
    u = (u + 0x7fffu + ((u >> 16) & 1u)) >> 16;   // RNE
    return (unsigned short)u;
}
__device__ __forceinline__ float bf2f(unsigned short h) {
    return __uint_as_float(((unsigned)h) << 16);
}
// HW packed f32->bf16 (RNE on gfx950); dst.lo16=cvt(a), dst.hi16=cvt(b)
__device__ __forceinline__ unsigned cvtpk(float a, float b) {
    unsigned r;
    asm("v_cvt_pk_bf16_f32 %0, %1, %2" : "=v"(r) : "v"(a), "v"(b));
    return r;
}
// 4 fp32 -> packed bf16 hi plane (4x16b) + lo plane (residual, 4x16b)
__device__ __forceinline__ void pack_hilo(float f0, float f1, float f2, float f3,
                                          ull& hi, ull& lo) {
    const unsigned h01 = cvtpk(f0, f1), h23 = cvtpk(f2, f3);
    const float l0 = f0 - __uint_as_float(h01 << 16);
    const float l1 = f1 - __uint_as_float(h01 & 0xffff0000u);
    const float l2 = f2 - __uint_as_float(h23 << 16);
    const float l3 = f3 - __uint_as_float(h23 & 0xffff0000u);
    const unsigned q01 = cvtpk(l0, l1), q23 = cvtpk(l2, l3);
    hi = (ull)h01 | ((ull)h23 << 32);
    lo = (ull)q01 | ((ull)q23 << 32);
}
__device__ __forceinline__ void st_ag_u32(void* p, unsigned v) {
    __hip_atomic_store((unsigned*)p, v, __ATOMIC_RELAXED, __HIP_MEMORY_SCOPE_AGENT);
}
__device__ __forceinline__ unsigned ld_ag_u32(const void* p) {
    return __hip_atomic_load((const unsigned*)p, __ATOMIC_RELAXED, __HIP_MEMORY_SCOPE_AGENT);
}
// L3-coherence-point (bypass L1+L2) data ops
__device__ __forceinline__ uintx4 ld_l3_b128_async(const void* p) {
    uintx4 v;
    asm volatile("global_load_dwordx4 %0, %1, off sc0 sc1"
                 : "=v"(v) : "v"(p) : "memory");
    return v;
}
__device__ __forceinline__ void st_l3_b32(void* p, unsigned v) {
    asm volatile("global_store_dword %0, %1, off sc0 sc1"
                 :: "v"(p), "v"(v) : "memory");
}
__device__ __forceinline__ void st_l3_b128(void* p, uintx4 v) {
    asm volatile("global_store_dwordx4 %0, %1, off sc0 sc1"
                 :: "v"(p), "v"(v) : "memory");
}
__device__ __forceinline__ void wait_vm0() {
    asm volatile("s_waitcnt vmcnt(0)" ::: "memory");
}
__device__ __forceinline__ void poll_flag(const unsigned* p, unsigned want) {
    int it = 0;
    for (;;) {
        unsigned f = ld_ag_u32(p);
        if (f == want || f == want + 1u) return;
        if (++it >= POLL_CAP) return;            // tags still protect data
    }
}

__global__ __launch_bounds__(256, 1) void rnn_persistent(
    const float* __restrict__ x,     const float* __restrict__ W_ih,
    const float* __restrict__ W_hh,  const float* __restrict__ b_ih,
    const float* __restrict__ b_hh,  const float* __restrict__ fc_w,
    const float* __restrict__ fc_b,  float* __restrict__ out,
    unsigned char* __restrict__ ws)
{
    const int tid  = threadIdx.x;
    const int lane = tid & 63;
    const int w    = tid >> 6;        // wave 0..3
    const int n    = lane & 15;
    const int quad = lane >> 4;

    const int bid = blockIdx.x;
    const int g = bid >> 2;           // group 0..15
    const int m = bid & 3;            // member 0..3

    unsigned char* ex = (unsigned char*)ws;
    unsigned* flagbase = (unsigned*)(ex + FLAGS_OFF + g * 64);
    __shared__ __align__(16) unsigned char smem[LX_OFF + 2 * LX_PLANE];
    __shared__ unsigned sh_nonce;

    // ---- nonce publish (single self-validating dword: low byte 0x5B) ----
    unsigned* nonce_p = (unsigned*)(ex + NEG_OFF);
    if (tid == 0) {
        if (bid == 0) {
            unsigned nn = ((unsigned)__builtin_amdgcn_s_memrealtime() << 8) | 0x5Bu;
            st_ag_u32(nonce_p, nn);
        }
        unsigned v; int it = 0;
        do { v = ld_ag_u32(nonce_p); } while ((v & 0xFFu) != 0x5Bu && ++it < NEG_CAP);
        sh_nonce = v;
    }
    __syncthreads();
    const unsigned nonce = sh_nonce;

    // ---- W fragments: wave w holds out-cols m*128+w*32+{0,16}+n ----
    const int wrow0 = m * 128 + w * 32 + n;
    const int wrow1 = wrow0 + 16;
    short8 Whi0[18], Wlo0[18], Whi1[18], Wlo1[18];
    #pragma unroll
    for (int kt = 0; kt < 18; ++kt) {
        const float* p0 = (kt < 16) ? (W_hh + wrow0 * 512 + kt * 32 + quad * 8)
                                    : (W_ih + wrow0 * 64 + (kt - 16) * 32 + quad * 8);
        const float* p1 = (kt < 16) ? (W_hh + wrow1 * 512 + kt * 32 + quad * 8)
                                    : (W_ih + wrow1 * 64 + (kt - 16) * 32 + quad * 8);
        #pragma unroll
        for (int jj = 0; jj < 8; ++jj) {
            float f0 = p0[jj];
            unsigned short h0 = f2bf(f0);
            Whi0[kt][jj] = (short)h0;
            Wlo0[kt][jj] = (short)f2bf(f0 - bf2f(h0));
            float f1 = p1[jj];
            unsigned short h1 = f2bf(f1);
            Whi1[kt][jj] = (short)h1;
            Wlo1[kt][jj] = (short)f2bf(f1 - bf2f(h1));
        }
    }
    const float bias0 = b_ih[wrow0] + b_hh[wrow0];
    const float bias1 = b_ih[wrow1] + b_hh[wrow1];

    // ---- per-thread partner span mapping: 3 partners x 2 halves x 16B ----
    const int prow = tid >> 4, pc4 = tid & 15;
    int poff[6];
    #pragma unroll
    for (int r = 0; r < 3; ++r) {
        const int pm = r + (r >= m ? 1 : 0);
        poff[2 * r]     = prow * 2048 + pm * 512 + pc4 * 16;
        poff[2 * r + 1] = prow * 2048 + pm * 512 + 256 + pc4 * 16;
    }

    // ---- init: own chunk = +0.0 (tag0) in parity-0 slab; own LDS cols = 0
    {
        uintx4 z = {0u, 0u, 0u, 0u};
        st_l3_b128(ex + g * SLAB + prow * 2048 + m * 512 + pc4 * 16, z);
        st_l3_b128(ex + g * SLAB + prow * 2048 + m * 512 + 256 + pc4 * 16, z);
        #pragma unroll
        for (int r = 0; r < 4; ++r) {
            const int row = quad * 4 + r;
            *(unsigned short*)(smem + row * LA_STRIDE + wrow0 * 2) = 0;
            *(unsigned short*)(smem + LA_PLANE + row * LA_STRIDE + wrow0 * 2) = 0;
            *(unsigned short*)(smem + row * LA_STRIDE + wrow1 * 2) = 0;
            *(unsigned short*)(smem + LA_PLANE + row * LA_STRIDE + wrow1 * 2) = 0;
        }
    }
    wait_vm0();
    __syncthreads();
    if (tid == 0) st_ag_u32(flagbase + m, nonce);

    // ---- recurrence ------------------------------------------------------
    const int xrow = tid >> 4, xi4 = tid & 15;
    for (int t = 0; t < T_STEPS; ++t) {
        const unsigned texp = (((unsigned)t >> 1) & 1u) << 31;
        const unsigned char* slab_r = ex + ((t & 1) * NG + g) * SLAB;

        // phase-1: speculative partner loads (overlap the flag park)
        uintx4 P[6];
        #pragma unroll
        for (int r = 0; r < 6; ++r) P[r] = ld_l3_b128_async(slab_r + poff[r]);
        // x_t load (independent, cacheable)
        const float4 xv = *(const float4*)
            (x + ((size_t)(g * 16 + xrow) * T_STEPS + t) * 64 + xi4 * 4);

        // flag park (3 threads only - no data-poll storm)
        if (tid < 3) {
            const int pm = tid + (tid >= m ? 1 : 0);
            poll_flag(flagbase + pm, nonce + (unsigned)t);
        }
        wait_vm0();
        __syncthreads();                                   // (a)

        // phase-2: bounded per-thread tag-retry for stale spans
        {
            int it = 0;
            for (;;) {
                unsigned bad = 0;
                #pragma unroll
                for (int r = 0; r < 6; ++r)
                    bad |= (P[r].x ^ texp) | (P[r].y ^ texp)
                         | (P[r].z ^ texp) | (P[r].w ^ texp);
                if (!(bad & 0x80000000u) || ++it >= TAG_CAP) break;
                #pragma unroll
                for (int r = 0; r < 6; ++r) P[r] = ld_l3_b128_async(slab_r + poff[r]);
                wait_vm0();
            }
        }

        // convert partner cols -> LDS A planes (parity t&1)
        unsigned char* abase = smem + (t & 1) * LA_PAR;
        #pragma unroll
        for (int r = 0; r < 6; ++r) {
            const int pp = r >> 1;
            const int pm = pp + (pp >= m ? 1 : 0);
            const int half = r & 1;
            ull hi, lo;
            pack_hilo(__uint_as_float(P[r].x & 0x7fffffffu),
                      __uint_as_float(P[r].y & 0x7fffffffu),
                      __uint_as_float(P[r].z & 0x7fffffffu),
                      __uint_as_float(P[r].w & 0x7fffffffu), hi, lo);
            const int base = prow * LA_STRIDE + pm * 256 + half * 128 + pc4 * 8;
            *(ull*)(abase + base)            = hi;
            *(ull*)(abase + LA_PLANE + base) = lo;
        }
        // stage x_t (fp32 -> bf16 hi/lo)
        {
            ull hi, lo;
            pack_hilo(xv.x, xv.y, xv.z, xv.w, hi, lo);
            *(ull*)(smem + LX_OFF + xrow * LX_STRIDE + xi4 * 8)            = hi;
            *(ull*)(smem + LX_OFF + LX_PLANE + xrow * LX_STRIDE + xi4 * 8) = lo;
        }
        __syncthreads();                                   // (b)

        // MFMA: 2 col-tiles of C[16 batch x 16 cols] over K=576, bf16x3
        floatx4 c00 = {0.f,0.f,0.f,0.f}, c01 = {0.f,0.f,0.f,0.f}, c02 = {0.f,0.f,0.f,0.f};
        floatx4 c10 = {0.f,0.f,0.f,0.f}, c11 = {0.f,0.f,0.f,0.f}, c12 = {0.f,0.f,0.f,0.f};
        #pragma unroll
        for (int kt = 0; kt < 16; ++kt) {
            const unsigned char* ba = abase + n * LA_STRIDE + kt * 64 + quad * 16;
            short8 ah = *(const short8*)(ba);
            short8 al = *(const short8*)(ba + LA_PLANE);
            c00 = __builtin_amdgcn_mfma_f32_16x16x32_bf16(ah, Whi0[kt], c00, 0, 0, 0);
            c01 = __builtin_amdgcn_mfma_f32_16x16x32_bf16(al, Whi0[kt], c01, 0, 0, 0);
            c02 = __builtin_amdgcn_mfma_f32_16x16x32_bf16(ah, Wlo0[kt], c02, 0, 0, 0);
            c10 = __builtin_amdgcn_mfma_f32_16x16x32_bf16(ah, Whi1[kt], c10, 0, 0, 0);
            c11 = __builtin_amdgcn_mfma_f32_16x16x32_bf16(al, Whi1[kt], c11, 0, 0, 0);
            c12 = __builtin_amdgcn_mfma_f32_16x16x32_bf16(ah, Wlo1[kt], c12, 0, 0, 0);
        }
        #pragma unroll
        for (int kt = 16; kt < 18; ++kt) {
            const unsigned char* ba = smem + LX_OFF + n * LX_STRIDE + (kt - 16) * 64 + quad * 16;
            short8 ah = *(const short8*)(ba);
            short8 al = *(const short8*)(ba + LX_PLANE);
            c00 = __builtin_amdgcn_mfma_f32_16x16x32_bf16(ah, Whi0[kt], c00, 0, 0, 0);
            c01 = __builtin_amdgcn_mfma_f32_16x16x32_bf16(al, Whi0[kt], c01, 0, 0, 0);
            c02 = __builtin_amdgcn_mfma_f32_16x16x32_bf16(ah, Wlo0[kt], c02, 0, 0, 0);
            c10 = __builtin_amdgcn_mfma_f32_16x16x32_bf16(ah, Whi1[kt], c10, 0, 0, 0);
            c11 = __builtin_amdgcn_mfma_f32_16x16x32_bf16(al, Whi1[kt], c11, 0, 0, 0);
            c12 = __builtin_amdgcn_mfma_f32_16x16x32_bf16(ah, Wlo1[kt], c12, 0, 0, 0);
        }

        // epilogue: own cols h_{t+1} -> LDS parity (t+1)&1 + tagged global.
        // NO drain, NO wait: tags carry freshness; flag is only a throttle.
        const unsigned otag = ((((unsigned)t + 1u) >> 1) & 1u) << 31;
        unsigned char* slab_w = ex + (((t + 1) & 1) * NG + g) * SLAB;
        unsigned char* obase  = smem + ((t + 1) & 1) * LA_PAR;
        const int r0 = quad * 4;
        {   // tile 0
            const floatx4 cs = c00 + c01 + c02;
            const float v0 = fmaxf(cs[0] + bias0, 0.f);
            const float v1 = fmaxf(cs[1] + bias0, 0.f);
            const float v2 = fmaxf(cs[2] + bias0, 0.f);
            const float v3 = fmaxf(cs[3] + bias0, 0.f);
            const unsigned h01 = cvtpk(v0, v1), h23 = cvtpk(v2, v3);
            const float l0 = v0 - __uint_as_float(h01 << 16);
            const float l1 = v1 - __uint_as_float(h01 & 0xffff0000u);
            const float l2 = v2 - __uint_as_float(h23 << 16);
            const float l3 = v3 - __uint_as_float(h23 & 0xffff0000u);
            const unsigned q01 = cvtpk(l0, l1), q23 = cvtpk(l2, l3);
            *(unsigned short*)(obase + (r0+0) * LA_STRIDE + wrow0 * 2) = (unsigned short)(h01 & 0xffffu);
            *(unsigned short*)(obase + (r0+1) * LA_STRIDE + wrow0 * 2) = (unsigned short)(h01 >> 16);
            *(unsigned short*)(obase + (r0+2) * LA_STRIDE + wrow0 * 2) = (unsigned short)(h23 & 0xffffu);
            *(unsigned short*)(obase + (r0+3) * LA_STRIDE + wrow0 * 2) = (unsigned short)(h23 >> 16);
            *(unsigned short*)(obase + LA_PLANE + (r0+0) * LA_STRIDE + wrow0 * 2) = (unsigned short)(q01 & 0xffffu);
            *(unsigned short*)(obase + LA_PLANE + (r0+1) * LA_STRIDE + wrow0 * 2) = (unsigned short)(q01 >> 16);
            *(unsigned short*)(obase + LA_PLANE + (r0+2) * LA_STRIDE + wrow0 * 2) = (unsigned short)(q23 & 0xffffu);
            *(unsigned short*)(obase + LA_PLANE + (r0+3) * LA_STRIDE + wrow0 * 2) = (unsigned short)(q23 >> 16);
            st_l3_b32(slab_w + (r0+0) * 2048 + wrow0 * 4, __float_as_uint(v0) | otag);
            st_l3_b32(slab_w + (r0+1) * 2048 + wrow0 * 4, __float_as_uint(v1) | otag);
            st_l3_b32(slab_w + (r0+2) * 2048 + wrow0 * 4, __float_as_uint(v2) | otag);
            st_l3_b32(slab_w + (r0+3) * 2048 + wrow0 * 4, __float_as_uint(v3) | otag);
        }
        {   // tile 1
            const floatx4 cs = c10 + c11 + c12;
            const float v0 = fmaxf(cs[0] + bias1, 0.f);
            const float v1 = fmaxf(cs[1] + bias1, 0.f);
            const float v2 = fmaxf(cs[2] + bias1, 0.f);
            const float v3 = fmaxf(cs[3] + bias1, 0.f);
            const unsigned h01 = cvtpk(v0, v1), h23 = cvtpk(v2, v3);
            const float l0 = v0 - __uint_as_float(h01 << 16);
            const float l1 = v1 - __uint_as_float(h01 & 0xffff0000u);
            const float l2 = v2 - __uint_as_float(h23 << 16);
            const float l3 = v3 - __uint_as_float(h23 & 0xffff0000u);
            const unsigned q01 = cvtpk(l0, l1), q23 = cvtpk(l2, l3);
            *(unsigned short*)(obase + (r0+0) * LA_STRIDE + wrow1 * 2) = (unsigned short)(h01 & 0xffffu);
            *(unsigned short*)(obase + (r0+1) * LA_STRIDE + wrow1 * 2) = (unsigned short)(h01 >> 16);
            *(unsigned short*)(obase + (r0+2) * LA_STRIDE + wrow1 * 2) = (unsigned short)(h23 & 0xffffu);
            *(unsigned short*)(obase + (r0+3) * LA_STRIDE + wrow1 * 2) = (unsigned short)(h23 >> 16);
            *(unsigned short*)(obase + LA_PLANE + (r0+0) * LA_STRIDE + wrow1 * 2) = (unsigned short)(q01 & 0xffffu);
            *(unsigned short*)(obase + LA_PLANE + (r0+1) * LA_STRIDE + wrow1 * 2) = (unsigned short)(q01 >> 16);
            *(unsigned short*)(obase + LA_PLANE + (r0+2) * LA_STRIDE + wrow1 * 2) = (unsigned short)(q23 & 0xffffu);
            *(unsigned short*)(obase + LA_PLANE + (r0+3) * LA_STRIDE + wrow1 * 2) = (unsigned short)(q23 >> 16);
            st_l3_b32(slab_w + (r0+0) * 2048 + wrow1 * 4, __float_as_uint(v0) | otag);
            st_l3_b32(slab_w + (r0+1) * 2048 + wrow1 * 4, __float_as_uint(v1) | otag);
            st_l3_b32(slab_w + (r0+2) * 2048 + wrow1 * 4, __float_as_uint(v2) | otag);
            st_l3_b32(slab_w + (r0+3) * 2048 + wrow1 * 4, __float_as_uint(v3) | otag);
        }
        if (tid == 0) st_ag_u32(flagbase + m, nonce + (unsigned)t + 1u);
    }

    // ---- fc on h_512 (member 0 only; own cols already in LDS parity 0) ---
    if (m != 0) return;
    {
        const unsigned texp = 0;                           // tag of h_512
        const unsigned char* slab_r = ex + (0 * NG + g) * SLAB;
        uintx4 P[6];
        #pragma unroll
        for (int r = 0; r < 6; ++r) P[r] = ld_l3_b128_async(slab_r + poff[r]);
        if (tid < 3) poll_flag(flagbase + (tid + 1), nonce + (unsigned)T_STEPS);
        wait_vm0();
        __syncthreads();
        int it = 0;
        for (;;) {
            unsigned bad = 0;
            #pragma unroll
            for (int r = 0; r < 6; ++r)
                bad |= (P[r].x ^ texp) | (P[r].y ^ texp)
                     | (P[r].z ^ texp) | (P[r].w ^ texp);
            if (!(bad & 0x80000000u) || ++it >= TAG_CAP) break;
            #pragma unroll
            for (int r = 0; r < 6; ++r) P[r] = ld_l3_b128_async(slab_r + poff[r]);
            wait_vm0();
        }
        unsigned char* abase = smem;                       // parity 0
        #pragma unroll
        for (int r = 0; r < 6; ++r) {
            const int pm = (r >> 1) + 1;
            const int half = r & 1;
            ull hi, lo;
            pack_hilo(__uint_as_float(P[r].x & 0x7fffffffu),
                      __uint_as_float(P[r].y & 0x7fffffffu),
                      __uint_as_float(P[r].z & 0x7fffffffu),
                      __uint_as_float(P[r].w & 0x7fffffffu), hi, lo);
            const int base = prow * LA_STRIDE + pm * 256 + half * 128 + pc4 * 8;
            *(ull*)(abase + base)            = hi;
            *(ull*)(abase + LA_PLANE + base) = lo;
        }
    }
    __syncthreads();
    for (int idx = tid; idx < 384; idx += 256) {
        const int row = idx / 24, o = idx % 24;
        const float* wp = fc_w + o * 512;
        float s = 0.f;
        for (int k = 0; k < 512; k += 4) {
            bfx4 hv = *(const bfx4*)(smem + row * LA_STRIDE + k * 2);
            bfx4 lv = *(const bfx4*)(smem + LA_PLANE + row * LA_STRIDE + k * 2);
            const float4 wv = *(const float4*)(wp + k);
            s += (bf2f(hv[0]) + bf2f(lv[0])) * wv.x;
            s += (bf2f(hv[1]) + bf2f(lv[1])) * wv.y;
            s += (bf2f(hv[2]) + bf2f(lv[2])) * wv.z;
            s += (bf2f(hv[3]) + bf2f(lv[3])) * wv.w;
        }
        out[(g * 16 + row) * 24 + o] = s + fc_b[o];
    }
}

extern "C" void kernel_launch(void* const* d_in, const int* in_sizes, int n_in,
                              void* d_out, int out_size, void* d_ws, size_t ws_size,
                              hipStream_t stream) {
    (void)in_sizes; (void)n_in; (void)out_size; (void)ws_size;
    const float* x    = (const float*)d_in[0];
    const float* W_ih = (const float*)d_in[1];
    const float* W_hh = (const float*)d_in[2];
    const float* b_ih = (const float*)d_in[3];
    const float* b_hh = (const float*)d_in[4];
    const float* fc_w = (const float*)d_in[5];
    const float* fc_b = (const float*)d_in[6];
    rnn_persistent<<<NG * NM, 256, 0, stream>>>(x, W_ih, W_hh, b_ih, b_hh,
                                                fc_w, fc_b, (float*)d_out,
                                                (unsigned char*)d_ws);
}

// Round 5
// 1529.436 us; speedup vs baseline: 1.2686x; 1.2686x over previous
//
#include <hip/hip_runtime.h>

// ---------------------------------------------------------------------------
// ReLU-RNN (B=256, T=512, I=64, H=512, O=24), fp32 in/out.  Round 10.
//
// 16 groups (16 batch rows) x 8 members (64 hid cols) = 128 blocks x 256 thr.
//   [round-10] = round-7 protocol/geometry EXACTLY (verified 1642us) +
//               v_cvt_pk_bf16_f32 packing (verified bit-identical, round 8).
//   [round-10] round-9 sc0-only L2 fast path REVERTED: failed correctness
//               (absmax 0.898) -- sc0-only visibility across CUs is NOT
//               sufficient under observed placement.  sc0 sc1 (L3 point)
//               + agent-scope flags is the verified-coherent protocol.
//   [round-10] NM=4 REVERTED (round 8: traffic halved, time +18% ->
//               exchange is latency-bound, not bandwidth-bound).
// Exchange = tagged fp32 (sign bit = slab-parity tag; h>=0 after relu):
//   * flags (agent-scope, 7 polling threads) throttle the wait
//   * sign-bit tags carry data-freshness correctness
//   * phase-1 SPECULATIVE partner loads issued before the poll
//   * phase-2 bounded per-thread tag-retry fixes stale spans
//   * producer: tagged dword stores + flag store with NO vmcnt drain.
// LDS A-planes double-buffered by parity -> 2 barriers/step.
// W_ext=[W_hh|W_ih] (K=576) in VGPRs as bf16 hi/lo frags; bf16x3 MFMA.
// ---------------------------------------------------------------------------

#define T_STEPS 512
#define NG      16
#define NM      8
#define SLAB    32768                    // 16 rows x 512 cols fp32
#define FLAGS_OFF (2 * NG * SLAB)        // 1 MiB
#define NEG_OFF  (FLAGS_OFF + NG * 64)
#define POLL_CAP 100000
#define TAG_CAP  20000
#define NEG_CAP  20000000

// LDS: A planes double-buffered by parity; rows 16 x 1040B (512 bf16 + 8 pad)
#define LA_STRIDE 1040
#define LA_PLANE  16640                  // 16*1040
#define LA_PAR    33280                  // 2*LA_PLANE (hi+lo)
#define LX_OFF    66560                  // 2*LA_PAR
#define LX_STRIDE 144
#define LX_PLANE  2304                   // 16*144; total 71168 B

typedef short          short8  __attribute__((ext_vector_type(8)));
typedef unsigned short bfx4    __attribute__((ext_vector_type(4)));
typedef unsigned       uintx4  __attribute__((ext_vector_type(4)));
typedef float          floatx4 __attribute__((ext_vector_type(4)));
typedef unsigned long long ull;

__device__ __forceinline__ unsigned short f2bf(float x) {
    unsigned u = __float_as_uint(x);
    u = (u + 0x7fffu + ((u >> 16) & 1u)) >> 16;   // RNE
    return (unsigned short)u;
}
__device__ __forceinline__ float bf2f(unsigned short h) {
    return __uint_as_float(((unsigned)h) << 16);
}
// HW packed f32->bf16 (RNE); dst.lo16=cvt(a), dst.hi16=cvt(b)
__device__ __forceinline__ unsigned cvtpk(float a, float b) {
    unsigned r;
    asm("v_cvt_pk_bf16_f32 %0, %1, %2" : "=v"(r) : "v"(a), "v"(b));
    return r;
}
// 4 fp32 -> packed bf16 hi plane (4x16b) + lo plane (residual, 4x16b)
__device__ __forceinline__ void pack_hilo(float f0, float f1, float f2, float f3,
                                          ull& hi, ull& lo) {
    const unsigned h01 = cvtpk(f0, f1), h23 = cvtpk(f2, f3);
    const float l0 = f0 - __uint_as_float(h01 << 16);
    const float l1 = f1 - __uint_as_float(h01 & 0xffff0000u);
    const float l2 = f2 - __uint_as_float(h23 << 16);
    const float l3 = f3 - __uint_as_float(h23 & 0xffff0000u);
    const unsigned q01 = cvtpk(l0, l1), q23 = cvtpk(l2, l3);
    hi = (ull)h01 | ((ull)h23 << 32);
    lo = (ull)q01 | ((ull)q23 << 32);
}
__device__ __forceinline__ void st_ag_u32(void* p, unsigned v) {
    __hip_atomic_store((unsigned*)p, v, __ATOMIC_RELAXED, __HIP_MEMORY_SCOPE_AGENT);
}
__device__ __forceinline__ unsigned ld_ag_u32(const void* p) {
    return __hip_atomic_load((const unsigned*)p, __ATOMIC_RELAXED, __HIP_MEMORY_SCOPE_AGENT);
}
// L3-coherence-point (bypass L1+L2) data ops
__device__ __forceinline__ uintx4 ld_l3_b128_async(const void* p) {
    uintx4 v;
    asm volatile("global_load_dwordx4 %0, %1, off sc0 sc1"
                 : "=v"(v) : "v"(p) : "memory");
    return v;
}
__device__ __forceinline__ void st_l3_b32(void* p, unsigned v) {
    asm volatile("global_store_dword %0, %1, off sc0 sc1"
                 :: "v"(p), "v"(v) : "memory");
}
__device__ __forceinline__ void st_l3_b128(void* p, uintx4 v) {
    asm volatile("global_store_dwordx4 %0, %1, off sc0 sc1"
                 :: "v"(p), "v"(v) : "memory");
}
__device__ __forceinline__ void wait_vm0() {
    asm volatile("s_waitcnt vmcnt(0)" ::: "memory");
}
__device__ __forceinline__ void poll_flag(const unsigned* p, unsigned want) {
    int it = 0;
    for (;;) {
        unsigned f = ld_ag_u32(p);
        if (f == want || f == want + 1u) return;
        if (++it >= POLL_CAP) return;            // tags still protect data
    }
}

__global__ __launch_bounds__(256, 1) void rnn_persistent(
    const float* __restrict__ x,     const float* __restrict__ W_ih,
    const float* __restrict__ W_hh,  const float* __restrict__ b_ih,
    const float* __restrict__ b_hh,  const float* __restrict__ fc_w,
    const float* __restrict__ fc_b,  float* __restrict__ out,
    unsigned char* __restrict__ ws)
{
    const int tid  = threadIdx.x;
    const int lane = tid & 63;
    const int w    = tid >> 6;        // wave 0..3
    const int n    = lane & 15;
    const int quad = lane >> 4;

    const int bid = blockIdx.x;
    const int g = bid >> 3;           // group 0..15
    const int m = bid & 7;            // member 0..7

    unsigned char* ex = (unsigned char*)ws;
    unsigned* flagbase = (unsigned*)(ex + FLAGS_OFF + g * 64);
    __shared__ __align__(16) unsigned char smem[LX_OFF + 2 * LX_PLANE];
    __shared__ unsigned sh_nonce;

    // ---- nonce publish (single self-validating dword: low byte 0x5B) ----
    unsigned* nonce_p = (unsigned*)(ex + NEG_OFF);
    if (tid == 0) {
        if (bid == 0) {
            unsigned nn = ((unsigned)__builtin_amdgcn_s_memrealtime() << 8) | 0x5Bu;
            st_ag_u32(nonce_p, nn);
        }
        unsigned v; int it = 0;
        do { v = ld_ag_u32(nonce_p); } while ((v & 0xFFu) != 0x5Bu && ++it < NEG_CAP);
        sh_nonce = v;
    }
    __syncthreads();
    const unsigned nonce = sh_nonce;

    // ---- W fragments: wave w holds cols (=W rows) m*64+w*16 .. +16 ----
    const int wrow = m * 64 + w * 16 + n;
    short8 Whi[18], Wlo[18];
    #pragma unroll
    for (int kt = 0; kt < 18; ++kt) {
        const float* p = (kt < 16) ? (W_hh + wrow * 512 + kt * 32 + quad * 8)
                                   : (W_ih + wrow * 64 + (kt - 16) * 32 + quad * 8);
        #pragma unroll
        for (int jj = 0; jj < 8; ++jj) {
            float f = p[jj];
            unsigned short h = f2bf(f);
            Whi[kt][jj] = (short)h;
            Wlo[kt][jj] = (short)f2bf(f - bf2f(h));
        }
    }
    const float bias_i = b_ih[wrow] + b_hh[wrow];

    // ---- per-thread partner span mapping (row prow, 16B at pc4) ----
    const int prow = tid >> 4, pc4 = tid & 15;
    int poff[7];
    #pragma unroll
    for (int r = 0; r < 7; ++r) {
        const int pm = r + (r >= m ? 1 : 0);
        poff[r] = prow * 2048 + pm * 256 + pc4 * 16;
    }

    // ---- init: own chunk = +0.0 (tag0) in parity-0 slab; own LDS cols = 0
    {
        uintx4 z = {0u, 0u, 0u, 0u};
        st_l3_b128(ex + g * SLAB + prow * 2048 + m * 256 + pc4 * 16, z);
        #pragma unroll
        for (int r = 0; r < 4; ++r) {
            const int row = quad * 4 + r;
            *(unsigned short*)(smem + 0 * LA_PLANE + row * LA_STRIDE + wrow * 2) = 0;
            *(unsigned short*)(smem + LA_PLANE + row * LA_STRIDE + wrow * 2) = 0;
        }
    }
    wait_vm0();
    __syncthreads();
    if (tid == 0) st_ag_u32(flagbase + m, nonce);

    // ---- recurrence ------------------------------------------------------
    const int xrow = tid >> 4, xi4 = tid & 15;
    for (int t = 0; t < T_STEPS; ++t) {
        const unsigned texp = (((unsigned)t >> 1) & 1u) << 31;
        const unsigned char* slab_r = ex + ((t & 1) * NG + g) * SLAB;

        // phase-1: speculative partner loads (overlap the flag park)
        uintx4 P[7];
        #pragma unroll
        for (int r = 0; r < 7; ++r) P[r] = ld_l3_b128_async(slab_r + poff[r]);
        // x_t load (independent, cacheable)
        const float4 xv = *(const float4*)
            (x + ((size_t)(g * 16 + xrow) * T_STEPS + t) * 64 + xi4 * 4);

        // flag park (7 threads only - no data-poll storm)
        if (tid < 7) {
            const int pm = tid + (tid >= m ? 1 : 0);
            poll_flag(flagbase + pm, nonce + (unsigned)t);
        }
        wait_vm0();
        __syncthreads();                                   // (a)

        // phase-2: bounded per-thread tag-retry for stale spans
        {
            int it = 0;
            for (;;) {
                unsigned bad = 0;
                #pragma unroll
                for (int r = 0; r < 7; ++r)
                    bad |= (P[r].x ^ texp) | (P[r].y ^ texp)
                         | (P[r].z ^ texp) | (P[r].w ^ texp);
                if (!(bad & 0x80000000u) || ++it >= TAG_CAP) break;
                #pragma unroll
                for (int r = 0; r < 7; ++r) P[r] = ld_l3_b128_async(slab_r + poff[r]);
                wait_vm0();
            }
        }

        // convert partner cols -> LDS A planes (parity t&1)
        unsigned char* abase = smem + (t & 1) * LA_PAR;
        #pragma unroll
        for (int r = 0; r < 7; ++r) {
            const int pm = r + (r >= m ? 1 : 0);
            ull hi, lo;
            pack_hilo(__uint_as_float(P[r].x & 0x7fffffffu),
                      __uint_as_float(P[r].y & 0x7fffffffu),
                      __uint_as_float(P[r].z & 0x7fffffffu),
                      __uint_as_float(P[r].w & 0x7fffffffu), hi, lo);
            const int base = prow * LA_STRIDE + pm * 128 + pc4 * 8;
            *(ull*)(abase + base)            = hi;
            *(ull*)(abase + LA_PLANE + base) = lo;
        }
        // stage x_t (fp32 -> bf16 hi/lo)
        {
            ull hi, lo;
            pack_hilo(xv.x, xv.y, xv.z, xv.w, hi, lo);
            *(ull*)(smem + LX_OFF + xrow * LX_STRIDE + xi4 * 8)            = hi;
            *(ull*)(smem + LX_OFF + LX_PLANE + xrow * LX_STRIDE + xi4 * 8) = lo;
        }
        __syncthreads();                                   // (b)

        // MFMA: C[16 batch x 16 cols] over K=576, bf16x3
        floatx4 c0 = {0.f,0.f,0.f,0.f}, c1 = {0.f,0.f,0.f,0.f}, c2 = {0.f,0.f,0.f,0.f};
        #pragma unroll
        for (int kt = 0; kt < 16; ++kt) {
            const unsigned char* ba = abase + n * LA_STRIDE + kt * 64 + quad * 16;
            short8 ah = *(const short8*)(ba);
            short8 al = *(const short8*)(ba + LA_PLANE);
            c0 = __builtin_amdgcn_mfma_f32_16x16x32_bf16(ah, Whi[kt], c0, 0, 0, 0);
            c1 = __builtin_amdgcn_mfma_f32_16x16x32_bf16(al, Whi[kt], c1, 0, 0, 0);
            c2 = __builtin_amdgcn_mfma_f32_16x16x32_bf16(ah, Wlo[kt], c2, 0, 0, 0);
        }
        #pragma unroll
        for (int kt = 16; kt < 18; ++kt) {
            const unsigned char* ba = smem + LX_OFF + n * LX_STRIDE + (kt - 16) * 64 + quad * 16;
            short8 ah = *(const short8*)(ba);
            short8 al = *(const short8*)(ba + LX_PLANE);
            c0 = __builtin_amdgcn_mfma_f32_16x16x32_bf16(ah, Whi[kt], c0, 0, 0, 0);
            c1 = __builtin_amdgcn_mfma_f32_16x16x32_bf16(al, Whi[kt], c1, 0, 0, 0);
            c2 = __builtin_amdgcn_mfma_f32_16x16x32_bf16(ah, Wlo[kt], c2, 0, 0, 0);
        }

        // epilogue: own cols h_{t+1} -> LDS parity (t+1)&1 + tagged global.
        // NO drain, NO wait: tags carry freshness; flag is only a throttle.
        const unsigned otag = ((((unsigned)t + 1u) >> 1) & 1u) << 31;
        unsigned char* slab_w = ex + (((t + 1) & 1) * NG + g) * SLAB;
        unsigned char* obase  = smem + ((t + 1) & 1) * LA_PAR;
        const floatx4 cs = c0 + c1 + c2;
        const int r0 = quad * 4;
        {
            const float v0 = fmaxf(cs[0] + bias_i, 0.f);
            const float v1 = fmaxf(cs[1] + bias_i, 0.f);
            const float v2 = fmaxf(cs[2] + bias_i, 0.f);
            const float v3 = fmaxf(cs[3] + bias_i, 0.f);
            const unsigned h01 = cvtpk(v0, v1), h23 = cvtpk(v2, v3);
            const float l0 = v0 - __uint_as_float(h01 << 16);
            const float l1 = v1 - __uint_as_float(h01 & 0xffff0000u);
            const float l2 = v2 - __uint_as_float(h23 << 16);
            const float l3 = v3 - __uint_as_float(h23 & 0xffff0000u);
            const unsigned q01 = cvtpk(l0, l1), q23 = cvtpk(l2, l3);
            *(unsigned short*)(obase + (r0+0) * LA_STRIDE + wrow * 2) = (unsigned short)(h01 & 0xffffu);
            *(unsigned short*)(obase + (r0+1) * LA_STRIDE + wrow * 2) = (unsigned short)(h01 >> 16);
            *(unsigned short*)(obase + (r0+2) * LA_STRIDE + wrow * 2) = (unsigned short)(h23 & 0xffffu);
            *(unsigned short*)(obase + (r0+3) * LA_STRIDE + wrow * 2) = (unsigned short)(h23 >> 16);
            *(unsigned short*)(obase + LA_PLANE + (r0+0) * LA_STRIDE + wrow * 2) = (unsigned short)(q01 & 0xffffu);
            *(unsigned short*)(obase + LA_PLANE + (r0+1) * LA_STRIDE + wrow * 2) = (unsigned short)(q01 >> 16);
            *(unsigned short*)(obase + LA_PLANE + (r0+2) * LA_STRIDE + wrow * 2) = (unsigned short)(q23 & 0xffffu);
            *(unsigned short*)(obase + LA_PLANE + (r0+3) * LA_STRIDE + wrow * 2) = (unsigned short)(q23 >> 16);
            st_l3_b32(slab_w + (r0+0) * 2048 + wrow * 4, __float_as_uint(v0) | otag);
            st_l3_b32(slab_w + (r0+1) * 2048 + wrow * 4, __float_as_uint(v1) | otag);
            st_l3_b32(slab_w + (r0+2) * 2048 + wrow * 4, __float_as_uint(v2) | otag);
            st_l3_b32(slab_w + (r0+3) * 2048 + wrow * 4, __float_as_uint(v3) | otag);
        }
        if (tid == 0) st_ag_u32(flagbase + m, nonce + (unsigned)t + 1u);
    }

    // ---- fc on h_512 (member 0 only; own cols already in LDS parity 0) ---
    if (m != 0) return;
    {
        const unsigned texp = 0;                           // tag of h_512
        const unsigned char* slab_r = ex + (0 * NG + g) * SLAB;
        uintx4 P[7];
        #pragma unroll
        for (int r = 0; r < 7; ++r) P[r] = ld_l3_b128_async(slab_r + poff[r]);
        if (tid < 7) poll_flag(flagbase + (tid + 1), nonce + (unsigned)T_STEPS);
        wait_vm0();
        __syncthreads();
        int it = 0;
        for (;;) {
            unsigned bad = 0;
            #pragma unroll
            for (int r = 0; r < 7; ++r)
                bad |= (P[r].x ^ texp) | (P[r].y ^ texp)
                     | (P[r].z ^ texp) | (P[r].w ^ texp);
            if (!(bad & 0x80000000u) || ++it >= TAG_CAP) break;
            #pragma unroll
            for (int r = 0; r < 7; ++r) P[r] = ld_l3_b128_async(slab_r + poff[r]);
            wait_vm0();
        }
        unsigned char* abase = smem;                       // parity 0
        #pragma unroll
        for (int r = 0; r < 7; ++r) {
            const int pm = r + 1;
            ull hi, lo;
            pack_hilo(__uint_as_float(P[r].x & 0x7fffffffu),
                      __uint_as_float(P[r].y & 0x7fffffffu),
                      __uint_as_float(P[r].z & 0x7fffffffu),
                      __uint_as_float(P[r].w & 0x7fffffffu), hi, lo);
            const int base = prow * LA_STRIDE + pm * 128 + pc4 * 8;
            *(ull*)(abase + base)            = hi;
            *(ull*)(abase + LA_PLANE + base) = lo;
        }
    }
    __syncthreads();
    for (int idx = tid; idx < 384; idx += 256) {
        const int row = idx / 24, o = idx % 24;
        const float* wp = fc_w + o * 512;
        float s = 0.f;
        for (int k = 0; k < 512; k += 4) {
            bfx4 hv = *(const bfx4*)(smem + row * LA_STRIDE + k * 2);
            bfx4 lv = *(const bfx4*)(smem + LA_PLANE + row * LA_STRIDE + k * 2);
            const float4 wv = *(const float4*)(wp + k);
            s += (bf2f(hv[0]) + bf2f(lv[0])) * wv.x;
            s += (bf2f(hv[1]) + bf2f(lv[1])) * wv.y;
            s += (bf2f(hv[2]) + bf2f(lv[2])) * wv.z;
            s += (bf2f(hv[3]) + bf2f(lv[3])) * wv.w;
        }
        out[(g * 16 + row) * 24 + o] = s + fc_b[o];
    }
}

extern "C" void kernel_launch(void* const* d_in, const int* in_sizes, int n_in,
                              void* d_out, int out_size, void* d_ws, size_t ws_size,
                              hipStream_t stream) {
    (void)in_sizes; (void)n_in; (void)out_size; (void)ws_size;
    const float* x    = (const float*)d_in[0];
    const float* W_ih = (const float*)d_in[1];
    const float* W_hh = (const float*)d_in[2];
    const float* b_ih = (const float*)d_in[3];
    const float* b_hh = (const float*)d_in[4];
    const float* fc_w = (const float*)d_in[5];
    const float* fc_b = (const float*)d_in[6];
    rnn_persistent<<<NG * NM, 256, 0, stream>>>(x, W_ih, W_hh, b_ih, b_hh,
                                                fc_w, fc_b, (float*)d_out,
                                                (unsigned char*)d_ws);
}

// Round 6
// 1438.468 us; speedup vs baseline: 1.3488x; 1.0632x over previous
//
#include <hip/hip_runtime.h>

// ---------------------------------------------------------------------------
// ReLU-RNN (B=256, T=512, I=64, H=512, O=24), fp32 in/out.  Round 11.
//
// 16 groups (16 batch rows) x 8 members (64 hid cols) = 128 blocks x 256 thr.
//   [round-11] x_t PREFETCH one step ahead into regs: the cold-HBM x load
//              (~900cy) no longer sits in the wait_vm0 drain on the step
//              critical path.  Issued after the tag-retry loop so retry
//              drains never wait on HBM.
//   [round-11] epilogue reorder: global tagged h-stores issue BEFORE the
//              LDS own-col writes -> producer visibility starts earlier.
//   [round-10] round-7 protocol + v_cvt_pk_bf16_f32 packing (verified
//              1529us, absmax 0.001953125).
// Exchange = tagged fp32 (sign bit = slab-parity tag; h>=0 after relu):
//   * flags (agent-scope, 7 polling threads) throttle the wait
//   * sign-bit tags carry data-freshness correctness
//   * phase-1 SPECULATIVE partner loads issued before the poll
//   * phase-2 bounded per-thread tag-retry fixes stale spans
//   * producer: tagged dword stores + flag store with NO vmcnt drain.
// LDS A-planes double-buffered by parity -> 2 barriers/step.
// W_ext=[W_hh|W_ih] (K=576) in VGPRs as bf16 hi/lo frags; bf16x3 MFMA.
// ---------------------------------------------------------------------------

#define T_STEPS 512
#define NG      16
#define NM      8
#define SLAB    32768                    // 16 rows x 512 cols fp32
#define FLAGS_OFF (2 * NG * SLAB)        // 1 MiB
#define NEG_OFF  (FLAGS_OFF + NG * 64)
#define POLL_CAP 100000
#define TAG_CAP  20000
#define NEG_CAP  20000000

// LDS: A planes double-buffered by parity; rows 16 x 1040B (512 bf16 + 8 pad)
#define LA_STRIDE 1040
#define LA_PLANE  16640                  // 16*1040
#define LA_PAR    33280                  // 2*LA_PLANE (hi+lo)
#define LX_OFF    66560                  // 2*LA_PAR
#define LX_STRIDE 144
#define LX_PLANE  2304                   // 16*144; total 71168 B

typedef short          short8  __attribute__((ext_vector_type(8)));
typedef unsigned short bfx4    __attribute__((ext_vector_type(4)));
typedef unsigned       uintx4  __attribute__((ext_vector_type(4)));
typedef float          floatx4 __attribute__((ext_vector_type(4)));
typedef unsigned long long ull;

__device__ __forceinline__ unsigned short f2bf(float x) {
    unsigned u = __float_as_uint(x);
    u = (u + 0x7fffu + ((u >> 16) & 1u)) >> 16;   // RNE
    return (unsigned short)u;
}
__device__ __forceinline__ float bf2f(unsigned short h) {
    return __uint_as_float(((unsigned)h) << 16);
}
// HW packed f32->bf16 (RNE); dst.lo16=cvt(a), dst.hi16=cvt(b)
__device__ __forceinline__ unsigned cvtpk(float a, float b) {
    unsigned r;
    asm("v_cvt_pk_bf16_f32 %0, %1, %2" : "=v"(r) : "v"(a), "v"(b));
    return r;
}
// 4 fp32 -> packed bf16 hi plane (4x16b) + lo plane (residual, 4x16b)
__device__ __forceinline__ void pack_hilo(float f0, float f1, float f2, float f3,
                                          ull& hi, ull& lo) {
    const unsigned h01 = cvtpk(f0, f1), h23 = cvtpk(f2, f3);
    const float l0 = f0 - __uint_as_float(h01 << 16);
    const float l1 = f1 - __uint_as_float(h01 & 0xffff0000u);
    const float l2 = f2 - __uint_as_float(h23 << 16);
    const float l3 = f3 - __uint_as_float(h23 & 0xffff0000u);
    const unsigned q01 = cvtpk(l0, l1), q23 = cvtpk(l2, l3);
    hi = (ull)h01 | ((ull)h23 << 32);
    lo = (ull)q01 | ((ull)q23 << 32);
}
__device__ __forceinline__ void st_ag_u32(void* p, unsigned v) {
    __hip_atomic_store((unsigned*)p, v, __ATOMIC_RELAXED, __HIP_MEMORY_SCOPE_AGENT);
}
__device__ __forceinline__ unsigned ld_ag_u32(const void* p) {
    return __hip_atomic_load((const unsigned*)p, __ATOMIC_RELAXED, __HIP_MEMORY_SCOPE_AGENT);
}
// L3-coherence-point (bypass L1+L2) data ops
__device__ __forceinline__ uintx4 ld_l3_b128_async(const void* p) {
    uintx4 v;
    asm volatile("global_load_dwordx4 %0, %1, off sc0 sc1"
                 : "=v"(v) : "v"(p) : "memory");
    return v;
}
__device__ __forceinline__ void st_l3_b32(void* p, unsigned v) {
    asm volatile("global_store_dword %0, %1, off sc0 sc1"
                 :: "v"(p), "v"(v) : "memory");
}
__device__ __forceinline__ void st_l3_b128(void* p, uintx4 v) {
    asm volatile("global_store_dwordx4 %0, %1, off sc0 sc1"
                 :: "v"(p), "v"(v) : "memory");
}
__device__ __forceinline__ void wait_vm0() {
    asm volatile("s_waitcnt vmcnt(0)" ::: "memory");
}
__device__ __forceinline__ void poll_flag(const unsigned* p, unsigned want) {
    int it = 0;
    for (;;) {
        unsigned f = ld_ag_u32(p);
        if (f == want || f == want + 1u) return;
        if (++it >= POLL_CAP) return;            // tags still protect data
    }
}

__global__ __launch_bounds__(256, 1) void rnn_persistent(
    const float* __restrict__ x,     const float* __restrict__ W_ih,
    const float* __restrict__ W_hh,  const float* __restrict__ b_ih,
    const float* __restrict__ b_hh,  const float* __restrict__ fc_w,
    const float* __restrict__ fc_b,  float* __restrict__ out,
    unsigned char* __restrict__ ws)
{
    const int tid  = threadIdx.x;
    const int lane = tid & 63;
    const int w    = tid >> 6;        // wave 0..3
    const int n    = lane & 15;
    const int quad = lane >> 4;

    const int bid = blockIdx.x;
    const int g = bid >> 3;           // group 0..15
    const int m = bid & 7;            // member 0..7

    unsigned char* ex = (unsigned char*)ws;
    unsigned* flagbase = (unsigned*)(ex + FLAGS_OFF + g * 64);
    __shared__ __align__(16) unsigned char smem[LX_OFF + 2 * LX_PLANE];
    __shared__ unsigned sh_nonce;

    // ---- nonce publish (single self-validating dword: low byte 0x5B) ----
    unsigned* nonce_p = (unsigned*)(ex + NEG_OFF);
    if (tid == 0) {
        if (bid == 0) {
            unsigned nn = ((unsigned)__builtin_amdgcn_s_memrealtime() << 8) | 0x5Bu;
            st_ag_u32(nonce_p, nn);
        }
        unsigned v; int it = 0;
        do { v = ld_ag_u32(nonce_p); } while ((v & 0xFFu) != 0x5Bu && ++it < NEG_CAP);
        sh_nonce = v;
    }
    __syncthreads();
    const unsigned nonce = sh_nonce;

    // ---- W fragments: wave w holds cols (=W rows) m*64+w*16 .. +16 ----
    const int wrow = m * 64 + w * 16 + n;
    short8 Whi[18], Wlo[18];
    #pragma unroll
    for (int kt = 0; kt < 18; ++kt) {
        const float* p = (kt < 16) ? (W_hh + wrow * 512 + kt * 32 + quad * 8)
                                   : (W_ih + wrow * 64 + (kt - 16) * 32 + quad * 8);
        #pragma unroll
        for (int jj = 0; jj < 8; ++jj) {
            float f = p[jj];
            unsigned short h = f2bf(f);
            Whi[kt][jj] = (short)h;
            Wlo[kt][jj] = (short)f2bf(f - bf2f(h));
        }
    }
    const float bias_i = b_ih[wrow] + b_hh[wrow];

    // ---- per-thread partner span mapping (row prow, 16B at pc4) ----
    const int prow = tid >> 4, pc4 = tid & 15;
    int poff[7];
    #pragma unroll
    for (int r = 0; r < 7; ++r) {
        const int pm = r + (r >= m ? 1 : 0);
        poff[r] = prow * 2048 + pm * 256 + pc4 * 16;
    }

    // ---- init: own chunk = +0.0 (tag0) in parity-0 slab; own LDS cols = 0
    {
        uintx4 z = {0u, 0u, 0u, 0u};
        st_l3_b128(ex + g * SLAB + prow * 2048 + m * 256 + pc4 * 16, z);
        #pragma unroll
        for (int r = 0; r < 4; ++r) {
            const int row = quad * 4 + r;
            *(unsigned short*)(smem + 0 * LA_PLANE + row * LA_STRIDE + wrow * 2) = 0;
            *(unsigned short*)(smem + LA_PLANE + row * LA_STRIDE + wrow * 2) = 0;
        }
    }
    wait_vm0();
    __syncthreads();
    if (tid == 0) st_ag_u32(flagbase + m, nonce);

    // ---- recurrence ------------------------------------------------------
    const int xrow = tid >> 4, xi4 = tid & 15;
    const float* xbase = x + (size_t)(g * 16 + xrow) * T_STEPS * 64 + xi4 * 4;
    // x prefetch: xv_cur holds x_t; load for t=0 up front (prologue only).
    float4 xv_cur = *(const float4*)(xbase + 0 * 64);
    for (int t = 0; t < T_STEPS; ++t) {
        const unsigned texp = (((unsigned)t >> 1) & 1u) << 31;
        const unsigned char* slab_r = ex + ((t & 1) * NG + g) * SLAB;

        // phase-1: speculative partner loads (overlap the flag park)
        uintx4 P[7];
        #pragma unroll
        for (int r = 0; r < 7; ++r) P[r] = ld_l3_b128_async(slab_r + poff[r]);

        // flag park (7 threads only - no data-poll storm)
        if (tid < 7) {
            const int pm = tid + (tid >= m ? 1 : 0);
            poll_flag(flagbase + pm, nonce + (unsigned)t);
        }
        wait_vm0();
        __syncthreads();                                   // (a)

        // phase-2: bounded per-thread tag-retry for stale spans
        {
            int it = 0;
            for (;;) {
                unsigned bad = 0;
                #pragma unroll
                for (int r = 0; r < 7; ++r)
                    bad |= (P[r].x ^ texp) | (P[r].y ^ texp)
                         | (P[r].z ^ texp) | (P[r].w ^ texp);
                if (!(bad & 0x80000000u) || ++it >= TAG_CAP) break;
                #pragma unroll
                for (int r = 0; r < 7; ++r) P[r] = ld_l3_b128_async(slab_r + poff[r]);
                wait_vm0();
            }
        }

        // x prefetch for t+1 (HBM; issued AFTER retry so no drain waits on it;
        // consumed next step => full-step latency hiding)
        const int tn = (t + 1 < T_STEPS) ? (t + 1) : (T_STEPS - 1);
        const float4 xv_nxt = *(const float4*)(xbase + (size_t)tn * 64);

        // convert partner cols -> LDS A planes (parity t&1)
        unsigned char* abase = smem + (t & 1) * LA_PAR;
        #pragma unroll
        for (int r = 0; r < 7; ++r) {
            const int pm = r + (r >= m ? 1 : 0);
            ull hi, lo;
            pack_hilo(__uint_as_float(P[r].x & 0x7fffffffu),
                      __uint_as_float(P[r].y & 0x7fffffffu),
                      __uint_as_float(P[r].z & 0x7fffffffu),
                      __uint_as_float(P[r].w & 0x7fffffffu), hi, lo);
            const int base = prow * LA_STRIDE + pm * 128 + pc4 * 8;
            *(ull*)(abase + base)            = hi;
            *(ull*)(abase + LA_PLANE + base) = lo;
        }
        // stage x_t (fp32 -> bf16 hi/lo) from prefetched regs
        {
            ull hi, lo;
            pack_hilo(xv_cur.x, xv_cur.y, xv_cur.z, xv_cur.w, hi, lo);
            *(ull*)(smem + LX_OFF + xrow * LX_STRIDE + xi4 * 8)            = hi;
            *(ull*)(smem + LX_OFF + LX_PLANE + xrow * LX_STRIDE + xi4 * 8) = lo;
        }
        __syncthreads();                                   // (b)

        // MFMA: C[16 batch x 16 cols] over K=576, bf16x3
        floatx4 c0 = {0.f,0.f,0.f,0.f}, c1 = {0.f,0.f,0.f,0.f}, c2 = {0.f,0.f,0.f,0.f};
        #pragma unroll
        for (int kt = 0; kt < 16; ++kt) {
            const unsigned char* ba = abase + n * LA_STRIDE + kt * 64 + quad * 16;
            short8 ah = *(const short8*)(ba);
            short8 al = *(const short8*)(ba + LA_PLANE);
            c0 = __builtin_amdgcn_mfma_f32_16x16x32_bf16(ah, Whi[kt], c0, 0, 0, 0);
            c1 = __builtin_amdgcn_mfma_f32_16x16x32_bf16(al, Whi[kt], c1, 0, 0, 0);
            c2 = __builtin_amdgcn_mfma_f32_16x16x32_bf16(ah, Wlo[kt], c2, 0, 0, 0);
        }
        #pragma unroll
        for (int kt = 16; kt < 18; ++kt) {
            const unsigned char* ba = smem + LX_OFF + n * LX_STRIDE + (kt - 16) * 64 + quad * 16;
            short8 ah = *(const short8*)(ba);
            short8 al = *(const short8*)(ba + LX_PLANE);
            c0 = __builtin_amdgcn_mfma_f32_16x16x32_bf16(ah, Whi[kt], c0, 0, 0, 0);
            c1 = __builtin_amdgcn_mfma_f32_16x16x32_bf16(al, Whi[kt], c1, 0, 0, 0);
            c2 = __builtin_amdgcn_mfma_f32_16x16x32_bf16(ah, Wlo[kt], c2, 0, 0, 0);
        }

        // epilogue: tagged GLOBAL stores first (producer visibility ASAP),
        // then LDS own-col writes.  NO drain: tags carry freshness.
        const unsigned otag = ((((unsigned)t + 1u) >> 1) & 1u) << 31;
        unsigned char* slab_w = ex + (((t + 1) & 1) * NG + g) * SLAB;
        unsigned char* obase  = smem + ((t + 1) & 1) * LA_PAR;
        const floatx4 cs = c0 + c1 + c2;
        const int r0 = quad * 4;
        {
            const float v0 = fmaxf(cs[0] + bias_i, 0.f);
            const float v1 = fmaxf(cs[1] + bias_i, 0.f);
            const float v2 = fmaxf(cs[2] + bias_i, 0.f);
            const float v3 = fmaxf(cs[3] + bias_i, 0.f);
            st_l3_b32(slab_w + (r0+0) * 2048 + wrow * 4, __float_as_uint(v0) | otag);
            st_l3_b32(slab_w + (r0+1) * 2048 + wrow * 4, __float_as_uint(v1) | otag);
            st_l3_b32(slab_w + (r0+2) * 2048 + wrow * 4, __float_as_uint(v2) | otag);
            st_l3_b32(slab_w + (r0+3) * 2048 + wrow * 4, __float_as_uint(v3) | otag);
            const unsigned h01 = cvtpk(v0, v1), h23 = cvtpk(v2, v3);
            const float l0 = v0 - __uint_as_float(h01 << 16);
            const float l1 = v1 - __uint_as_float(h01 & 0xffff0000u);
            const float l2 = v2 - __uint_as_float(h23 << 16);
            const float l3 = v3 - __uint_as_float(h23 & 0xffff0000u);
            const unsigned q01 = cvtpk(l0, l1), q23 = cvtpk(l2, l3);
            *(unsigned short*)(obase + (r0+0) * LA_STRIDE + wrow * 2) = (unsigned short)(h01 & 0xffffu);
            *(unsigned short*)(obase + (r0+1) * LA_STRIDE + wrow * 2) = (unsigned short)(h01 >> 16);
            *(unsigned short*)(obase + (r0+2) * LA_STRIDE + wrow * 2) = (unsigned short)(h23 & 0xffffu);
            *(unsigned short*)(obase + (r0+3) * LA_STRIDE + wrow * 2) = (unsigned short)(h23 >> 16);
            *(unsigned short*)(obase + LA_PLANE + (r0+0) * LA_STRIDE + wrow * 2) = (unsigned short)(q01 & 0xffffu);
            *(unsigned short*)(obase + LA_PLANE + (r0+1) * LA_STRIDE + wrow * 2) = (unsigned short)(q01 >> 16);
            *(unsigned short*)(obase + LA_PLANE + (r0+2) * LA_STRIDE + wrow * 2) = (unsigned short)(q23 & 0xffffu);
            *(unsigned short*)(obase + LA_PLANE + (r0+3) * LA_STRIDE + wrow * 2) = (unsigned short)(q23 >> 16);
        }
        if (tid == 0) st_ag_u32(flagbase + m, nonce + (unsigned)t + 1u);
        xv_cur = xv_nxt;
    }

    // ---- fc on h_512 (member 0 only; own cols already in LDS parity 0) ---
    if (m != 0) return;
    {
        const unsigned texp = 0;                           // tag of h_512
        const unsigned char* slab_r = ex + (0 * NG + g) * SLAB;
        uintx4 P[7];
        #pragma unroll
        for (int r = 0; r < 7; ++r) P[r] = ld_l3_b128_async(slab_r + poff[r]);
        if (tid < 7) poll_flag(flagbase + (tid + 1), nonce + (unsigned)T_STEPS);
        wait_vm0();
        __syncthreads();
        int it = 0;
        for (;;) {
            unsigned bad = 0;
            #pragma unroll
            for (int r = 0; r < 7; ++r)
                bad |= (P[r].x ^ texp) | (P[r].y ^ texp)
                     | (P[r].z ^ texp) | (P[r].w ^ texp);
            if (!(bad & 0x80000000u) || ++it >= TAG_CAP) break;
            #pragma unroll
            for (int r = 0; r < 7; ++r) P[r] = ld_l3_b128_async(slab_r + poff[r]);
            wait_vm0();
        }
        unsigned char* abase = smem;                       // parity 0
        #pragma unroll
        for (int r = 0; r < 7; ++r) {
            const int pm = r + 1;
            ull hi, lo;
            pack_hilo(__uint_as_float(P[r].x & 0x7fffffffu),
                      __uint_as_float(P[r].y & 0x7fffffffu),
                      __uint_as_float(P[r].z & 0x7fffffffu),
                      __uint_as_float(P[r].w & 0x7fffffffu), hi, lo);
            const int base = prow * LA_STRIDE + pm * 128 + pc4 * 8;
            *(ull*)(abase + base)            = hi;
            *(ull*)(abase + LA_PLANE + base) = lo;
        }
    }
    __syncthreads();
    for (int idx = tid; idx < 384; idx += 256) {
        const int row = idx / 24, o = idx % 24;
        const float* wp = fc_w + o * 512;
        float s = 0.f;
        for (int k = 0; k < 512; k += 4) {
            bfx4 hv = *(const bfx4*)(smem + row * LA_STRIDE + k * 2);
            bfx4 lv = *(const bfx4*)(smem + LA_PLANE + row * LA_STRIDE + k * 2);
            const float4 wv = *(const float4*)(wp + k);
            s += (bf2f(hv[0]) + bf2f(lv[0])) * wv.x;
            s += (bf2f(hv[1]) + bf2f(lv[1])) * wv.y;
            s += (bf2f(hv[2]) + bf2f(lv[2])) * wv.z;
            s += (bf2f(hv[3]) + bf2f(lv[3])) * wv.w;
        }
        out[(g * 16 + row) * 24 + o] = s + fc_b[o];
    }
}

extern "C" void kernel_launch(void* const* d_in, const int* in_sizes, int n_in,
                              void* d_out, int out_size, void* d_ws, size_t ws_size,
                              hipStream_t stream) {
    (void)in_sizes; (void)n_in; (void)out_size; (void)ws_size;
    const float* x    = (const float*)d_in[0];
    const float* W_ih = (const float*)d_in[1];
    const float* W_hh = (const float*)d_in[2];
    const float* b_ih = (const float*)d_in[3];
    const float* b_hh = (const float*)d_in[4];
    const float* fc_w = (const float*)d_in[5];
    const float* fc_b = (const float*)d_in[6];
    rnn_persistent<<<NG * NM, 256, 0, stream>>>(x, W_ih, W_hh, b_ih, b_hh,
                                                fc_w, fc_b, (float*)d_out,
                                                (unsigned char*)d_ws);
}